// Round 1
// baseline (3476.900 us; speedup 1.0000x reference)
//
#include <hip/hip_runtime.h>
#include <math.h>

#define Bb 32
#define Nn 128
#define Kk 48
#define Ff 256
#define Gg 50
#define Tt 3

__device__ __forceinline__ float ssp_f(float v) {
    // jax.nn.softplus(x) - log(2) == logaddexp(x,0) - log(2)
    return fmaxf(v, 0.f) + log1pf(expf(-fabsf(v))) - 0.69314718055994530942f;
}

// ---------------------------------------------------------------------------
// k_setup: x = embedding[z]; d, fexp, fcut per (b,n,k)
// grid: B*N blocks, 256 threads
// ---------------------------------------------------------------------------
__global__ __launch_bounds__(256) void k_setup(
    const float* __restrict__ pos, const int* __restrict__ zz,
    const int* __restrict__ nbr, const float* __restrict__ nmask,
    const float* __restrict__ emb,
    float* __restrict__ x, float* __restrict__ fexp, float* __restrict__ fcut)
{
    const int bn = blockIdx.x;
    const int b  = bn >> 7;           // N = 128
    const int t  = threadIdx.x;
    __shared__ float sd[Kk];

    // embedding gather
    x[bn * Ff + t] = emb[zz[bn] * Ff + t];

    if (t < Kk) {
        int j = nbr[bn * Kk + t];
        float px = pos[bn * 3 + 0], py = pos[bn * 3 + 1], pz = pos[bn * 3 + 2];
        int rj = (b * Nn + j) * 3;
        float dx = pos[rj + 0] - px;
        float dy = pos[rj + 1] - py;
        float dz = pos[rj + 2] - pz;
        float d = sqrtf(fmaf(dx, dx, fmaf(dy, dy, dz * dz)) + 1e-8f);
        sd[t] = d;
        float fc = 0.5f * (cosf(3.14159265358979323846f * d / 5.0f) + 1.0f);
        fc = (d < 5.0f) ? fc : 0.0f;
        fcut[bn * Kk + t] = fc * nmask[bn * Kk + t];
    }
    __syncthreads();

    const float step = 5.0f / 49.0f;
    const float coeff = -0.5f / (step * step);
    for (int i = t; i < Kk * Gg; i += 256) {
        int k = i / Gg, g = i - k * Gg;
        float dd = sd[k] - step * (float)g;
        fexp[bn * (Kk * Gg) + i] = expf(coeff * dd * dd);
    }
}

// ---------------------------------------------------------------------------
// k_y: y = x @ in2f_w[t]   (per-row matvec, 256 threads = output features)
// ---------------------------------------------------------------------------
__global__ __launch_bounds__(256) void k_y(
    const float* __restrict__ x, const float* __restrict__ w,
    float* __restrict__ y)
{
    const int bn = blockIdx.x;
    const int f  = threadIdx.x;
    __shared__ float sx[Ff];
    sx[f] = x[bn * Ff + f];
    __syncthreads();
    float acc = 0.f;
    #pragma unroll 8
    for (int h = 0; h < Ff; ++h) acc = fmaf(sx[h], w[h * Ff + f], acc);
    y[bn * Ff + f] = acc;
}

// ---------------------------------------------------------------------------
// k_agg: filter network + neighbor aggregation + fused f2out MLP residual
// grid: B*N blocks, 256 threads (thread = feature f)
// ---------------------------------------------------------------------------
__global__ __launch_bounds__(256) void k_agg(
    const float* __restrict__ fexp, const float* __restrict__ fcut,
    const int* __restrict__ nbr, const float* __restrict__ y,
    const float* __restrict__ w1, const float* __restrict__ b1,
    const float* __restrict__ w2, const float* __restrict__ b2,
    const float* __restrict__ fw1, const float* __restrict__ fb1,
    const float* __restrict__ fw2, const float* __restrict__ fb2,
    float* __restrict__ x)
{
    const int bn = blockIdx.x;
    const int b  = bn >> 7;
    const int f  = threadIdx.x;

    __shared__ float sfe[Kk][Gg];     // 9600 B
    __shared__ float sH[Kk][Ff];      // 49152 B
    __shared__ float scut[Kk];
    __shared__ int   snbr[Kk];
    __shared__ float sagg[Ff];
    __shared__ float sv[Ff];

    for (int i = f; i < Kk * Gg; i += 256) {
        int k = i / Gg, g = i - k * Gg;
        sfe[k][g] = fexp[bn * (Kk * Gg) + i];
    }
    if (f < Kk) {
        scut[f] = fcut[bn * Kk + f];
        snbr[f] = nbr[bn * Kk + f];
    }
    __syncthreads();

    // ---- filter layer 1: H[k][f] = ssp(fexp[k,:] @ w1[:,f] + b1[f]) ----
    {
        float w1r[Gg];
        #pragma unroll
        for (int g = 0; g < Gg; ++g) w1r[g] = w1[g * Ff + f];
        const float bb1 = b1[f];
        #pragma unroll 1
        for (int k = 0; k < Kk; ++k) {
            float h = bb1;
            #pragma unroll
            for (int g = 0; g < Gg; ++g) h = fmaf(sfe[k][g], w1r[g], h);
            sH[k][f] = ssp_f(h);
        }
    }
    __syncthreads();

    // ---- filter layer 2 + cutoff + neighbor aggregation ----
    float acc[Kk];
    #pragma unroll
    for (int k = 0; k < Kk; ++k) acc[k] = 0.f;

    #pragma unroll 1
    for (int h0 = 0; h0 < Ff; h0 += 8) {
        float w2r[8];
        #pragma unroll
        for (int j = 0; j < 8; ++j) w2r[j] = w2[(h0 + j) * Ff + f];
        #pragma unroll
        for (int k = 0; k < Kk; ++k) {
            #pragma unroll
            for (int j = 0; j < 8; ++j)
                acc[k] = fmaf(sH[k][h0 + j], w2r[j], acc[k]);
        }
    }

    const float bb2 = b2[f];
    float agg = 0.f;
    #pragma unroll 1
    for (int k = 0; k < Kk; ++k) {
        float wv = (acc[k] + bb2) * scut[k];
        agg = fmaf(wv, y[(b * Nn + snbr[k]) * Ff + f], agg);
    }

    // ---- fused f2out MLP residual: x += ssp(agg@fw1+fb1)@fw2 + fb2 ----
    sagg[f] = agg;
    __syncthreads();
    float u = fb1[f];
    #pragma unroll 8
    for (int h = 0; h < Ff; ++h) u = fmaf(sagg[h], fw1[h * Ff + f], u);
    sv[f] = ssp_f(u);
    __syncthreads();
    float o = fb2[f];
    #pragma unroll 8
    for (int h = 0; h < Ff; ++h) o = fmaf(sv[h], fw2[h * Ff + f], o);
    x[bn * Ff + f] += o;
}

// ---------------------------------------------------------------------------
// k_head: disp/frac/rep, predictor MLP, masked mean, new_cell, new_pos
// grid: B blocks, 128 threads (thread = atom n)
// ---------------------------------------------------------------------------
__global__ __launch_bounds__(128) void k_head(
    const float* __restrict__ x, const float* __restrict__ pos,
    const float* __restrict__ cell, const float* __restrict__ amask,
    const float* __restrict__ fdw, const float* __restrict__ fdb,
    const float* __restrict__ pw1, const float* __restrict__ pb1,
    const float* __restrict__ pw2, const float* __restrict__ pb2,
    float* __restrict__ out_pos, float* __restrict__ out_cell)
{
    const int b = blockIdx.x;
    const int n = threadIdx.x;

    __shared__ float sinv[9];
    __shared__ float scell[9];
    __shared__ float snc[9];
    __shared__ float sred[Nn][10];

    if (n == 0) {
        float c[9];
        #pragma unroll
        for (int i = 0; i < 9; ++i) { c[i] = cell[b * 9 + i]; scell[i] = c[i]; }
        float det = c[0] * (c[4] * c[8] - c[5] * c[7])
                  - c[1] * (c[3] * c[8] - c[5] * c[6])
                  + c[2] * (c[3] * c[7] - c[4] * c[6]);
        float id = 1.0f / det;
        sinv[0] = (c[4] * c[8] - c[5] * c[7]) * id;
        sinv[1] = (c[2] * c[7] - c[1] * c[8]) * id;
        sinv[2] = (c[1] * c[5] - c[2] * c[4]) * id;
        sinv[3] = (c[5] * c[6] - c[3] * c[8]) * id;
        sinv[4] = (c[0] * c[8] - c[2] * c[6]) * id;
        sinv[5] = (c[2] * c[3] - c[0] * c[5]) * id;
        sinv[6] = (c[3] * c[7] - c[4] * c[6]) * id;
        sinv[7] = (c[1] * c[6] - c[0] * c[7]) * id;
        sinv[8] = (c[0] * c[4] - c[1] * c[3]) * id;
    }
    __syncthreads();

    // disp = sigmoid(10*(x @ fd_w + fd_b))
    float xv0 = 0.f, xv1 = 0.f, xv2 = 0.f;
    const int row = (b * Nn + n) * Ff;
    for (int ff = 0; ff < Ff; ++ff) {
        float xr = x[row + ff];
        xv0 = fmaf(xr, fdw[ff * 3 + 0], xv0);
        xv1 = fmaf(xr, fdw[ff * 3 + 1], xv1);
        xv2 = fmaf(xr, fdw[ff * 3 + 2], xv2);
    }
    float fr[3];
    float dsp[3] = {xv0, xv1, xv2};
    const float p0 = pos[(b * Nn + n) * 3 + 0];
    const float p1 = pos[(b * Nn + n) * 3 + 1];
    const float p2 = pos[(b * Nn + n) * 3 + 2];
    #pragma unroll
    for (int j = 0; j < 3; ++j) {
        float z = 10.0f * (dsp[j] + fdb[j]);
        float s = 1.0f / (1.0f + expf(-z));
        float fx = p0 * sinv[0 * 3 + j] + p1 * sinv[1 * 3 + j] + p2 * sinv[2 * 3 + j] + s;
        fr[j] = fx - floorf(fx);   // mod 1.0
    }

    // rep = frac @ cell
    float rep[3];
    #pragma unroll
    for (int j = 0; j < 3; ++j)
        rep[j] = fr[0] * scell[0 * 3 + j] + fr[1] * scell[1 * 3 + j] + fr[2] * scell[2 * 3 + j];

    // predictor MLP 3 -> 6 -> 9
    float a6[6];
    #pragma unroll
    for (int i = 0; i < 6; ++i) {
        float u = rep[0] * pw1[0 * 6 + i] + rep[1] * pw1[1 * 6 + i]
                + rep[2] * pw1[2 * 6 + i] + pb1[i];
        a6[i] = ssp_f(u);
    }
    float h9[9];
    #pragma unroll
    for (int o = 0; o < 9; ++o) {
        float u = pb2[o];
        #pragma unroll
        for (int i = 0; i < 6; ++i) u = fmaf(a6[i], pw2[i * 9 + o], u);
        h9[o] = u;
    }

    const float m = amask[b * Nn + n];
    #pragma unroll
    for (int o = 0; o < 9; ++o) sred[n][o] = h9[o] * m;
    sred[n][9] = m;
    __syncthreads();

    for (int s = 64; s >= 1; s >>= 1) {
        if (n < s) {
            #pragma unroll
            for (int o = 0; o < 10; ++o) sred[n][o] += sred[n + s][o];
        }
        __syncthreads();
    }

    if (n < 9) {
        float na = sred[0][9];
        float yo = sred[0][n] / na;
        float scale = 3.0f * powf(na, 1.0f / 3.0f);
        int r = n / 3, c = n - r * 3;
        float v = scale * (((r == c) ? 1.0f : 0.0f) + yo);
        snc[n] = v;
        out_cell[b * 9 + n] = v;
    }
    __syncthreads();

    #pragma unroll
    for (int j = 0; j < 3; ++j) {
        float v = fr[0] * snc[0 * 3 + j] + fr[1] * snc[1 * 3 + j] + fr[2] * snc[2 * 3 + j];
        out_pos[(b * Nn + n) * 3 + j] = v;
    }
}

// ---------------------------------------------------------------------------
extern "C" void kernel_launch(void* const* d_in, const int* in_sizes, int n_in,
                              void* d_out, int out_size, void* d_ws, size_t ws_size,
                              hipStream_t stream)
{
    const float* positions     = (const float*)d_in[0];
    const float* cell          = (const float*)d_in[1];
    const int*   atomic_nums   = (const int*)  d_in[2];
    const int*   neighbors     = (const int*)  d_in[3];
    const float* neighbor_mask = (const float*)d_in[4];
    const float* atom_mask     = (const float*)d_in[5];
    const float* embedding     = (const float*)d_in[6];
    const float* filt_w1       = (const float*)d_in[7];
    const float* filt_b1       = (const float*)d_in[8];
    const float* filt_w2       = (const float*)d_in[9];
    const float* filt_b2       = (const float*)d_in[10];
    const float* in2f_w        = (const float*)d_in[11];
    const float* f2out_w1      = (const float*)d_in[12];
    const float* f2out_b1      = (const float*)d_in[13];
    const float* f2out_w2      = (const float*)d_in[14];
    const float* f2out_b2      = (const float*)d_in[15];
    const float* fd_w          = (const float*)d_in[16];
    const float* fd_b          = (const float*)d_in[17];
    const float* pred_w1       = (const float*)d_in[18];
    const float* pred_b1       = (const float*)d_in[19];
    const float* pred_w2       = (const float*)d_in[20];
    const float* pred_b2       = (const float*)d_in[21];

    float* ws   = (float*)d_ws;
    float* x    = ws;                       // B*N*F   = 1048576
    float* y    = x + Bb * Nn * Ff;         // B*N*F   = 1048576
    float* fexp = y + Bb * Nn * Ff;         // B*N*K*G = 9830400
    float* fcut = fexp + Bb * Nn * Kk * Gg; // B*N*K   = 196608

    float* out_pos  = (float*)d_out;
    float* out_cell = out_pos + Bb * Nn * 3;

    const int BN = Bb * Nn;

    k_setup<<<BN, 256, 0, stream>>>(positions, atomic_nums, neighbors,
                                    neighbor_mask, embedding, x, fexp, fcut);

    for (int t = 0; t < Tt; ++t) {
        k_y<<<BN, 256, 0, stream>>>(x, in2f_w + (size_t)t * Ff * Ff, y);
        k_agg<<<BN, 256, 0, stream>>>(fexp, fcut, neighbors, y,
                                      filt_w1 + (size_t)t * Gg * Ff,
                                      filt_b1 + (size_t)t * Ff,
                                      filt_w2 + (size_t)t * Ff * Ff,
                                      filt_b2 + (size_t)t * Ff,
                                      f2out_w1 + (size_t)t * Ff * Ff,
                                      f2out_b1 + (size_t)t * Ff,
                                      f2out_w2 + (size_t)t * Ff * Ff,
                                      f2out_b2 + (size_t)t * Ff,
                                      x);
    }

    k_head<<<Bb, 128, 0, stream>>>(x, positions, cell, atom_mask,
                                   fd_w, fd_b, pred_w1, pred_b1, pred_w2, pred_b2,
                                   out_pos, out_cell);
}

// Round 2
// 2288.521 us; speedup vs baseline: 1.5193x; 1.5193x over previous
//
#include <hip/hip_runtime.h>
#include <math.h>

#define Bb 32
#define Nn 128
#define Kk 48
#define KH 24          // K half-tile
#define Ff 256
#define Gg 50
#define Tt 3

__device__ __forceinline__ float ssp_f(float v) {
    // jax.nn.softplus(x) - log(2) == logaddexp(x,0) - log(2)
    return fmaxf(v, 0.f) + log1pf(expf(-fabsf(v))) - 0.69314718055994530942f;
}

// ---------------------------------------------------------------------------
// k_setup: x = embedding[z]; d, fexp, fcut per (b,n,k)
// ---------------------------------------------------------------------------
__global__ __launch_bounds__(256) void k_setup(
    const float* __restrict__ pos, const int* __restrict__ zz,
    const int* __restrict__ nbr, const float* __restrict__ nmask,
    const float* __restrict__ emb,
    float* __restrict__ x, float* __restrict__ fexp, float* __restrict__ fcut)
{
    const int bn = blockIdx.x;
    const int b  = bn >> 7;           // N = 128
    const int t  = threadIdx.x;
    __shared__ float sd[Kk];

    // embedding gather
    x[bn * Ff + t] = emb[zz[bn] * Ff + t];

    if (t < Kk) {
        int j = nbr[bn * Kk + t];
        float px = pos[bn * 3 + 0], py = pos[bn * 3 + 1], pz = pos[bn * 3 + 2];
        int rj = (b * Nn + j) * 3;
        float dx = pos[rj + 0] - px;
        float dy = pos[rj + 1] - py;
        float dz = pos[rj + 2] - pz;
        float d = sqrtf(fmaf(dx, dx, fmaf(dy, dy, dz * dz)) + 1e-8f);
        sd[t] = d;
        float fc = 0.5f * (cosf(3.14159265358979323846f * d / 5.0f) + 1.0f);
        fc = (d < 5.0f) ? fc : 0.0f;
        fcut[bn * Kk + t] = fc * nmask[bn * Kk + t];
    }
    __syncthreads();

    const float step = 5.0f / 49.0f;
    const float coeff = -0.5f / (step * step);
    for (int i = t; i < Kk * Gg; i += 256) {
        int k = i / Gg, g = i - k * Gg;
        float dd = sd[k] - step * (float)g;
        fexp[bn * (Kk * Gg) + i] = expf(coeff * dd * dd);
    }
}

// ---------------------------------------------------------------------------
// k_y: y = x @ in2f_w[t]
// ---------------------------------------------------------------------------
__global__ __launch_bounds__(256) void k_y(
    const float* __restrict__ x, const float* __restrict__ w,
    float* __restrict__ y)
{
    const int bn = blockIdx.x;
    const int f  = threadIdx.x;
    __shared__ __align__(16) float sx[Ff];
    sx[f] = x[bn * Ff + f];
    __syncthreads();
    float acc = 0.f;
    #pragma unroll 1
    for (int h0 = 0; h0 < Ff; h0 += 8) {
        const float4* xp = reinterpret_cast<const float4*>(&sx[h0]);
        float4 a = xp[0], c = xp[1];
        acc = fmaf(a.x, w[(h0 + 0) * Ff + f], acc);
        acc = fmaf(a.y, w[(h0 + 1) * Ff + f], acc);
        acc = fmaf(a.z, w[(h0 + 2) * Ff + f], acc);
        acc = fmaf(a.w, w[(h0 + 3) * Ff + f], acc);
        acc = fmaf(c.x, w[(h0 + 4) * Ff + f], acc);
        acc = fmaf(c.y, w[(h0 + 5) * Ff + f], acc);
        acc = fmaf(c.z, w[(h0 + 6) * Ff + f], acc);
        acc = fmaf(c.w, w[(h0 + 7) * Ff + f], acc);
    }
    y[bn * Ff + f] = acc;
}

// ---------------------------------------------------------------------------
// k_agg: filter network + neighbor aggregation + fused f2out MLP residual
// K processed in two halves of 24 so acc[] and sH fit registers / LDS.
// All acc[] loops fully unrolled (static indexing -> registers, rule #20).
// ---------------------------------------------------------------------------
__global__ __launch_bounds__(256, 4) void k_agg(
    const float* __restrict__ fexp, const float* __restrict__ fcut,
    const int* __restrict__ nbr, const float* __restrict__ y,
    const float* __restrict__ w1, const float* __restrict__ b1,
    const float* __restrict__ w2, const float* __restrict__ b2,
    const float* __restrict__ fw1, const float* __restrict__ fb1,
    const float* __restrict__ fw2, const float* __restrict__ fb2,
    float* __restrict__ x)
{
    const int bn = blockIdx.x;
    const int b  = bn >> 7;
    const int f  = threadIdx.x;

    __shared__ __align__(16) float sfe[Kk][Gg];   // 9600 B
    __shared__ __align__(16) float sH[KH][Ff];    // 24576 B
    __shared__ float scut[Kk];
    __shared__ int   snbr[Kk];
    __shared__ __align__(16) float sagg[Ff];
    __shared__ __align__(16) float sv[Ff];

    for (int i = f; i < Kk * Gg; i += 256) {
        int k = i / Gg, g = i - k * Gg;
        sfe[k][g] = fexp[bn * (Kk * Gg) + i];
    }
    if (f < Kk) {
        scut[f] = fcut[bn * Kk + f];
        snbr[f] = nbr[bn * Kk + f];
    }
    __syncthreads();

    const float bb1 = b1[f];
    const float bb2 = b2[f];
    float agg = 0.f;

    #pragma unroll
    for (int half = 0; half < 2; ++half) {
        const int kbase = half * KH;

        // ---- filter layer 1: sH[k][f] = ssp(fexp[kbase+k,:] @ w1[:,f] + b1) ----
        {
            float w1r[Gg];
            #pragma unroll
            for (int g = 0; g < Gg; ++g) w1r[g] = w1[g * Ff + f];
            #pragma unroll 1
            for (int k = 0; k < KH; ++k) {
                float h = bb1;
                #pragma unroll
                for (int g = 0; g < Gg; ++g) h = fmaf(sfe[kbase + k][g], w1r[g], h);
                sH[k][f] = ssp_f(h);
            }
        }
        __syncthreads();

        // ---- filter layer 2: acc[k] = sH[k,:] @ w2[:,f] ----
        float acc[KH];
        #pragma unroll
        for (int k = 0; k < KH; ++k) acc[k] = 0.f;

        #pragma unroll 1
        for (int h0 = 0; h0 < Ff; h0 += 8) {
            float w2r[8];
            #pragma unroll
            for (int j = 0; j < 8; ++j) w2r[j] = w2[(h0 + j) * Ff + f];
            #pragma unroll
            for (int k = 0; k < KH; ++k) {
                const float4* hp = reinterpret_cast<const float4*>(&sH[k][h0]);
                float4 h0v = hp[0];
                float4 h1v = hp[1];
                acc[k] = fmaf(h0v.x, w2r[0], acc[k]);
                acc[k] = fmaf(h0v.y, w2r[1], acc[k]);
                acc[k] = fmaf(h0v.z, w2r[2], acc[k]);
                acc[k] = fmaf(h0v.w, w2r[3], acc[k]);
                acc[k] = fmaf(h1v.x, w2r[4], acc[k]);
                acc[k] = fmaf(h1v.y, w2r[5], acc[k]);
                acc[k] = fmaf(h1v.z, w2r[6], acc[k]);
                acc[k] = fmaf(h1v.w, w2r[7], acc[k]);
            }
        }

        // ---- cutoff + neighbor aggregation (partial over this half) ----
        #pragma unroll
        for (int k = 0; k < KH; ++k) {
            float wv = (acc[k] + bb2) * scut[kbase + k];
            agg = fmaf(wv, y[(b * Nn + snbr[kbase + k]) * Ff + f], agg);
        }
        __syncthreads();   // before next half overwrites sH
    }

    // ---- fused f2out MLP residual: x += ssp(agg@fw1+fb1)@fw2 + fb2 ----
    sagg[f] = agg;
    __syncthreads();
    float u = fb1[f];
    #pragma unroll 1
    for (int h0 = 0; h0 < Ff; h0 += 8) {
        const float4* ap = reinterpret_cast<const float4*>(&sagg[h0]);
        float4 a = ap[0], c = ap[1];
        u = fmaf(a.x, fw1[(h0 + 0) * Ff + f], u);
        u = fmaf(a.y, fw1[(h0 + 1) * Ff + f], u);
        u = fmaf(a.z, fw1[(h0 + 2) * Ff + f], u);
        u = fmaf(a.w, fw1[(h0 + 3) * Ff + f], u);
        u = fmaf(c.x, fw1[(h0 + 4) * Ff + f], u);
        u = fmaf(c.y, fw1[(h0 + 5) * Ff + f], u);
        u = fmaf(c.z, fw1[(h0 + 6) * Ff + f], u);
        u = fmaf(c.w, fw1[(h0 + 7) * Ff + f], u);
    }
    sv[f] = ssp_f(u);
    __syncthreads();
    float o = fb2[f];
    #pragma unroll 1
    for (int h0 = 0; h0 < Ff; h0 += 8) {
        const float4* vp = reinterpret_cast<const float4*>(&sv[h0]);
        float4 a = vp[0], c = vp[1];
        o = fmaf(a.x, fw2[(h0 + 0) * Ff + f], o);
        o = fmaf(a.y, fw2[(h0 + 1) * Ff + f], o);
        o = fmaf(a.z, fw2[(h0 + 2) * Ff + f], o);
        o = fmaf(a.w, fw2[(h0 + 3) * Ff + f], o);
        o = fmaf(c.x, fw2[(h0 + 4) * Ff + f], o);
        o = fmaf(c.y, fw2[(h0 + 5) * Ff + f], o);
        o = fmaf(c.z, fw2[(h0 + 6) * Ff + f], o);
        o = fmaf(c.w, fw2[(h0 + 7) * Ff + f], o);
    }
    x[bn * Ff + f] += o;
}

// ---------------------------------------------------------------------------
// k_head: disp/frac/rep, predictor MLP, masked mean, new_cell, new_pos
// ---------------------------------------------------------------------------
__global__ __launch_bounds__(128) void k_head(
    const float* __restrict__ x, const float* __restrict__ pos,
    const float* __restrict__ cell, const float* __restrict__ amask,
    const float* __restrict__ fdw, const float* __restrict__ fdb,
    const float* __restrict__ pw1, const float* __restrict__ pb1,
    const float* __restrict__ pw2, const float* __restrict__ pb2,
    float* __restrict__ out_pos, float* __restrict__ out_cell)
{
    const int b = blockIdx.x;
    const int n = threadIdx.x;

    __shared__ float sinv[9];
    __shared__ float scell[9];
    __shared__ float snc[9];
    __shared__ float sred[Nn][10];

    if (n == 0) {
        float c[9];
        #pragma unroll
        for (int i = 0; i < 9; ++i) { c[i] = cell[b * 9 + i]; scell[i] = c[i]; }
        float det = c[0] * (c[4] * c[8] - c[5] * c[7])
                  - c[1] * (c[3] * c[8] - c[5] * c[6])
                  + c[2] * (c[3] * c[7] - c[4] * c[6]);
        float id = 1.0f / det;
        sinv[0] = (c[4] * c[8] - c[5] * c[7]) * id;
        sinv[1] = (c[2] * c[7] - c[1] * c[8]) * id;
        sinv[2] = (c[1] * c[5] - c[2] * c[4]) * id;
        sinv[3] = (c[5] * c[6] - c[3] * c[8]) * id;
        sinv[4] = (c[0] * c[8] - c[2] * c[6]) * id;
        sinv[5] = (c[2] * c[3] - c[0] * c[5]) * id;
        sinv[6] = (c[3] * c[7] - c[4] * c[6]) * id;
        sinv[7] = (c[1] * c[6] - c[0] * c[7]) * id;
        sinv[8] = (c[0] * c[4] - c[1] * c[3]) * id;
    }
    __syncthreads();

    // disp = sigmoid(10*(x @ fd_w + fd_b))
    float xv0 = 0.f, xv1 = 0.f, xv2 = 0.f;
    const int row = (b * Nn + n) * Ff;
    for (int ff = 0; ff < Ff; ++ff) {
        float xr = x[row + ff];
        xv0 = fmaf(xr, fdw[ff * 3 + 0], xv0);
        xv1 = fmaf(xr, fdw[ff * 3 + 1], xv1);
        xv2 = fmaf(xr, fdw[ff * 3 + 2], xv2);
    }
    float fr[3];
    float dsp[3] = {xv0, xv1, xv2};
    const float p0 = pos[(b * Nn + n) * 3 + 0];
    const float p1 = pos[(b * Nn + n) * 3 + 1];
    const float p2 = pos[(b * Nn + n) * 3 + 2];
    #pragma unroll
    for (int j = 0; j < 3; ++j) {
        float z = 10.0f * (dsp[j] + fdb[j]);
        float s = 1.0f / (1.0f + expf(-z));
        float fx = p0 * sinv[0 * 3 + j] + p1 * sinv[1 * 3 + j] + p2 * sinv[2 * 3 + j] + s;
        fr[j] = fx - floorf(fx);   // mod 1.0
    }

    // rep = frac @ cell
    float rep[3];
    #pragma unroll
    for (int j = 0; j < 3; ++j)
        rep[j] = fr[0] * scell[0 * 3 + j] + fr[1] * scell[1 * 3 + j] + fr[2] * scell[2 * 3 + j];

    // predictor MLP 3 -> 6 -> 9
    float a6[6];
    #pragma unroll
    for (int i = 0; i < 6; ++i) {
        float u = rep[0] * pw1[0 * 6 + i] + rep[1] * pw1[1 * 6 + i]
                + rep[2] * pw1[2 * 6 + i] + pb1[i];
        a6[i] = ssp_f(u);
    }
    float h9[9];
    #pragma unroll
    for (int o = 0; o < 9; ++o) {
        float u = pb2[o];
        #pragma unroll
        for (int i = 0; i < 6; ++i) u = fmaf(a6[i], pw2[i * 9 + o], u);
        h9[o] = u;
    }

    const float m = amask[b * Nn + n];
    #pragma unroll
    for (int o = 0; o < 9; ++o) sred[n][o] = h9[o] * m;
    sred[n][9] = m;
    __syncthreads();

    for (int s = 64; s >= 1; s >>= 1) {
        if (n < s) {
            #pragma unroll
            for (int o = 0; o < 10; ++o) sred[n][o] += sred[n + s][o];
        }
        __syncthreads();
    }

    if (n < 9) {
        float na = sred[0][9];
        float yo = sred[0][n] / na;
        float scale = 3.0f * powf(na, 1.0f / 3.0f);
        int r = n / 3, c = n - r * 3;
        float v = scale * (((r == c) ? 1.0f : 0.0f) + yo);
        snc[n] = v;
        out_cell[b * 9 + n] = v;
    }
    __syncthreads();

    #pragma unroll
    for (int j = 0; j < 3; ++j) {
        float v = fr[0] * snc[0 * 3 + j] + fr[1] * snc[1 * 3 + j] + fr[2] * snc[2 * 3 + j];
        out_pos[(b * Nn + n) * 3 + j] = v;
    }
}

// ---------------------------------------------------------------------------
extern "C" void kernel_launch(void* const* d_in, const int* in_sizes, int n_in,
                              void* d_out, int out_size, void* d_ws, size_t ws_size,
                              hipStream_t stream)
{
    const float* positions     = (const float*)d_in[0];
    const float* cell          = (const float*)d_in[1];
    const int*   atomic_nums   = (const int*)  d_in[2];
    const int*   neighbors     = (const int*)  d_in[3];
    const float* neighbor_mask = (const float*)d_in[4];
    const float* atom_mask     = (const float*)d_in[5];
    const float* embedding     = (const float*)d_in[6];
    const float* filt_w1       = (const float*)d_in[7];
    const float* filt_b1       = (const float*)d_in[8];
    const float* filt_w2       = (const float*)d_in[9];
    const float* filt_b2       = (const float*)d_in[10];
    const float* in2f_w        = (const float*)d_in[11];
    const float* f2out_w1      = (const float*)d_in[12];
    const float* f2out_b1      = (const float*)d_in[13];
    const float* f2out_w2      = (const float*)d_in[14];
    const float* f2out_b2      = (const float*)d_in[15];
    const float* fd_w          = (const float*)d_in[16];
    const float* fd_b          = (const float*)d_in[17];
    const float* pred_w1       = (const float*)d_in[18];
    const float* pred_b1       = (const float*)d_in[19];
    const float* pred_w2       = (const float*)d_in[20];
    const float* pred_b2       = (const float*)d_in[21];

    float* ws   = (float*)d_ws;
    float* x    = ws;                       // B*N*F   = 1048576
    float* y    = x + Bb * Nn * Ff;         // B*N*F   = 1048576
    float* fexp = y + Bb * Nn * Ff;         // B*N*K*G = 9830400
    float* fcut = fexp + Bb * Nn * Kk * Gg; // B*N*K   = 196608

    float* out_pos  = (float*)d_out;
    float* out_cell = out_pos + Bb * Nn * 3;

    const int BN = Bb * Nn;

    k_setup<<<BN, 256, 0, stream>>>(positions, atomic_nums, neighbors,
                                    neighbor_mask, embedding, x, fexp, fcut);

    for (int t = 0; t < Tt; ++t) {
        k_y<<<BN, 256, 0, stream>>>(x, in2f_w + (size_t)t * Ff * Ff, y);
        k_agg<<<BN, 256, 0, stream>>>(fexp, fcut, neighbors, y,
                                      filt_w1 + (size_t)t * Gg * Ff,
                                      filt_b1 + (size_t)t * Ff,
                                      filt_w2 + (size_t)t * Ff * Ff,
                                      filt_b2 + (size_t)t * Ff,
                                      f2out_w1 + (size_t)t * Ff * Ff,
                                      f2out_b1 + (size_t)t * Ff,
                                      f2out_w2 + (size_t)t * Ff * Ff,
                                      f2out_b2 + (size_t)t * Ff,
                                      x);
    }

    k_head<<<Bb, 128, 0, stream>>>(x, positions, cell, atom_mask,
                                   fd_w, fd_b, pred_w1, pred_b1, pred_w2, pred_b2,
                                   out_pos, out_cell);
}

// Round 4
// 1477.992 us; speedup vs baseline: 2.3524x; 1.5484x over previous
//
#include <hip/hip_runtime.h>
#include <math.h>

#define Bb 32
#define Nn 128
#define Kk 48
#define Ff 256
#define Gg 50
#define GP 52          // padded sfe row stride (208 B, 16-aligned)
#define Tt 3

__device__ __forceinline__ float ssp_f(float v) {
    return fmaxf(v, 0.f) + log1pf(expf(-fabsf(v))) - 0.69314718055994530942f;
}

// dst[4] += s * vv.{x,y,z,w}   (param must NOT be named like a member!)
#define FMA4(dst, s, vv)                      \
    dst[0] = fmaf((s), (vv).x, dst[0]);       \
    dst[1] = fmaf((s), (vv).y, dst[1]);       \
    dst[2] = fmaf((s), (vv).z, dst[2]);       \
    dst[3] = fmaf((s), (vv).w, dst[3]);

// ---------------------------------------------------------------------------
// k_setup: x = embedding[z]; d, fexp, fcut per (b,n,k)
// ---------------------------------------------------------------------------
__global__ __launch_bounds__(256) void k_setup(
    const float* __restrict__ pos, const int* __restrict__ zz,
    const int* __restrict__ nbr, const float* __restrict__ nmask,
    const float* __restrict__ emb,
    float* __restrict__ x, float* __restrict__ fexp, float* __restrict__ fcut)
{
    const int bn = blockIdx.x;
    const int b  = bn >> 7;
    const int t  = threadIdx.x;
    __shared__ float sd[Kk];

    x[bn * Ff + t] = emb[zz[bn] * Ff + t];

    if (t < Kk) {
        int j = nbr[bn * Kk + t];
        float px = pos[bn * 3 + 0], py = pos[bn * 3 + 1], pz = pos[bn * 3 + 2];
        int rj = (b * Nn + j) * 3;
        float dx = pos[rj + 0] - px;
        float dy = pos[rj + 1] - py;
        float dz = pos[rj + 2] - pz;
        float d = sqrtf(fmaf(dx, dx, fmaf(dy, dy, dz * dz)) + 1e-8f);
        sd[t] = d;
        float fc = 0.5f * (cosf(3.14159265358979323846f * d / 5.0f) + 1.0f);
        fc = (d < 5.0f) ? fc : 0.0f;
        fcut[bn * Kk + t] = fc * nmask[bn * Kk + t];
    }
    __syncthreads();

    const float step = 5.0f / 49.0f;
    const float coeff = -0.5f / (step * step);
    for (int i = t; i < Kk * Gg; i += 256) {
        int k = i / Gg, g = i - k * Gg;
        float dd = sd[k] - step * (float)g;
        fexp[bn * (Kk * Gg) + i] = expf(coeff * dd * dd);
    }
}

// ---------------------------------------------------------------------------
// k_y: y = x @ in2f_w[t]   — f-quad × h-split tiling
// ---------------------------------------------------------------------------
__global__ __launch_bounds__(256) void k_y(
    const float* __restrict__ x, const float* __restrict__ w,
    float* __restrict__ y)
{
    const int bn  = blockIdx.x;
    const int tid = threadIdx.x;
    const int tx  = tid & 63;
    const int ty  = tid >> 6;
    const int f4  = tx * 4;

    __shared__ __align__(16) float sx[Ff];
    __shared__ __align__(16) float p4[4][Ff];

    sx[tid] = x[bn * Ff + tid];
    __syncthreads();

    float p[4] = {0.f, 0.f, 0.f, 0.f};
    #pragma unroll 1
    for (int hh = 0; hh < 64; hh += 8) {
        const int h0 = ty * 64 + hh;
        float4 wq[8];
        #pragma unroll
        for (int j = 0; j < 8; ++j)
            wq[j] = *reinterpret_cast<const float4*>(&w[(h0 + j) * Ff + f4]);
        const float4 a0 = *reinterpret_cast<const float4*>(&sx[h0]);
        const float4 a1 = *reinterpret_cast<const float4*>(&sx[h0 + 4]);
        FMA4(p, a0.x, wq[0]); FMA4(p, a0.y, wq[1]);
        FMA4(p, a0.z, wq[2]); FMA4(p, a0.w, wq[3]);
        FMA4(p, a1.x, wq[4]); FMA4(p, a1.y, wq[5]);
        FMA4(p, a1.z, wq[6]); FMA4(p, a1.w, wq[7]);
    }
    *reinterpret_cast<float4*>(&p4[ty][f4]) = make_float4(p[0], p[1], p[2], p[3]);
    __syncthreads();
    y[bn * Ff + tid] = p4[0][tid] + p4[1][tid] + p4[2][tid] + p4[3][tid];
}

// ---------------------------------------------------------------------------
// k_agg: filter network + aggregation + fused f2out, f-quad × k-split tiling
// thread (tx,ty): f-quad = 4*tx, k in {12*ty .. 12*ty+11}
// ---------------------------------------------------------------------------
__global__ __launch_bounds__(256, 2) void k_agg(
    const float* __restrict__ fexp, const float* __restrict__ fcut,
    const int* __restrict__ nbr, const float* __restrict__ y,
    const float* __restrict__ w1, const float* __restrict__ b1,
    const float* __restrict__ w2, const float* __restrict__ b2,
    const float* __restrict__ fw1, const float* __restrict__ fb1,
    const float* __restrict__ fw2, const float* __restrict__ fb2,
    float* __restrict__ x)
{
    const int bn  = blockIdx.x;
    const int b   = bn >> 7;
    const int tid = threadIdx.x;
    const int tx  = tid & 63;
    const int ty  = tid >> 6;
    const int f4  = tx * 4;
    const int kb  = ty * 12;

    __shared__ __align__(16) float sH[Kk][Ff];        // 48 KB
    __shared__ __align__(16) union UU {
        float sfe[Kk][GP];                            // 9984 B (layer1 only)
        struct { float p4[4][Ff]; float red[Ff]; } r; // 5 KB (post-layer2)
    } u;
    __shared__ float scut[Kk];
    __shared__ int   snbr[Kk];

    for (int i = tid; i < Kk * Gg; i += 256) {
        int k = i / Gg, g = i - k * Gg;
        u.sfe[k][g] = fexp[bn * (Kk * Gg) + i];
    }
    if (tid < Kk) {
        scut[tid] = fcut[bn * Kk + tid];
        snbr[tid] = nbr[bn * Kk + tid];
    }
    __syncthreads();

    // ---- filter layer 1: h1[kk][i] = fexp[k,:] @ w1[:, f4+i] + b1 ----
    float h1[12][4];
    {
        const float4 bq = *reinterpret_cast<const float4*>(&b1[f4]);
        #pragma unroll
        for (int kk = 0; kk < 12; ++kk) {
            h1[kk][0] = bq.x; h1[kk][1] = bq.y; h1[kk][2] = bq.z; h1[kk][3] = bq.w;
        }
        #pragma unroll 1
        for (int c = 0; c < 6; ++c) {
            const int g0 = c * 8;
            float4 w1q[8];
            #pragma unroll
            for (int j = 0; j < 8; ++j)
                w1q[j] = *reinterpret_cast<const float4*>(&w1[(g0 + j) * Ff + f4]);
            #pragma unroll
            for (int kk = 0; kk < 12; ++kk) {
                const float4 fe0 = *reinterpret_cast<const float4*>(&u.sfe[kb + kk][g0]);
                const float4 fe1 = *reinterpret_cast<const float4*>(&u.sfe[kb + kk][g0 + 4]);
                FMA4(h1[kk], fe0.x, w1q[0]); FMA4(h1[kk], fe0.y, w1q[1]);
                FMA4(h1[kk], fe0.z, w1q[2]); FMA4(h1[kk], fe0.w, w1q[3]);
                FMA4(h1[kk], fe1.x, w1q[4]); FMA4(h1[kk], fe1.y, w1q[5]);
                FMA4(h1[kk], fe1.z, w1q[6]); FMA4(h1[kk], fe1.w, w1q[7]);
            }
        }
        // tail g = 48, 49
        const float4 w1a = *reinterpret_cast<const float4*>(&w1[48 * Ff + f4]);
        const float4 w1b = *reinterpret_cast<const float4*>(&w1[49 * Ff + f4]);
        #pragma unroll
        for (int kk = 0; kk < 12; ++kk) {
            const float fa = u.sfe[kb + kk][48];
            const float fb = u.sfe[kb + kk][49];
            FMA4(h1[kk], fa, w1a);
            FMA4(h1[kk], fb, w1b);
        }
    }
    // ssp + store H tile
    #pragma unroll
    for (int kk = 0; kk < 12; ++kk) {
        float4 hv;
        hv.x = ssp_f(h1[kk][0]); hv.y = ssp_f(h1[kk][1]);
        hv.z = ssp_f(h1[kk][2]); hv.w = ssp_f(h1[kk][3]);
        *reinterpret_cast<float4*>(&sH[kb + kk][f4]) = hv;
    }
    __syncthreads();

    // ---- filter layer 2: acc[kk][i] = H[k,:] @ w2[:, f4+i] ----
    float acc[12][4];
    #pragma unroll
    for (int kk = 0; kk < 12; ++kk) {
        acc[kk][0] = 0.f; acc[kk][1] = 0.f; acc[kk][2] = 0.f; acc[kk][3] = 0.f;
    }
    #pragma unroll 1
    for (int h0 = 0; h0 < Ff; h0 += 8) {
        float4 w2q[8];
        #pragma unroll
        for (int j = 0; j < 8; ++j)
            w2q[j] = *reinterpret_cast<const float4*>(&w2[(h0 + j) * Ff + f4]);
        #pragma unroll
        for (int kk = 0; kk < 12; ++kk) {
            const float4 s0 = *reinterpret_cast<const float4*>(&sH[kb + kk][h0]);
            const float4 s1 = *reinterpret_cast<const float4*>(&sH[kb + kk][h0 + 4]);
            FMA4(acc[kk], s0.x, w2q[0]); FMA4(acc[kk], s0.y, w2q[1]);
            FMA4(acc[kk], s0.z, w2q[2]); FMA4(acc[kk], s0.w, w2q[3]);
            FMA4(acc[kk], s1.x, w2q[4]); FMA4(acc[kk], s1.y, w2q[5]);
            FMA4(acc[kk], s1.z, w2q[6]); FMA4(acc[kk], s1.w, w2q[7]);
        }
    }

    // ---- cutoff + neighbor y gather ----
    const float4 b2q = *reinterpret_cast<const float4*>(&b2[f4]);
    float aggp[4] = {0.f, 0.f, 0.f, 0.f};
    #pragma unroll
    for (int kk = 0; kk < 12; ++kk) {
        const float ct = scut[kb + kk];
        const float4 yv = *reinterpret_cast<const float4*>(&y[(b * Nn + snbr[kb + kk]) * Ff + f4]);
        aggp[0] = fmaf((acc[kk][0] + b2q.x) * ct, yv.x, aggp[0]);
        aggp[1] = fmaf((acc[kk][1] + b2q.y) * ct, yv.y, aggp[1]);
        aggp[2] = fmaf((acc[kk][2] + b2q.z) * ct, yv.z, aggp[2]);
        aggp[3] = fmaf((acc[kk][3] + b2q.w) * ct, yv.w, aggp[3]);
    }
    *reinterpret_cast<float4*>(&u.r.p4[ty][f4]) =
        make_float4(aggp[0], aggp[1], aggp[2], aggp[3]);
    __syncthreads();

    // reduce over ty -> agg[f]
    {
        const float a = u.r.p4[0][tid] + u.r.p4[1][tid] + u.r.p4[2][tid] + u.r.p4[3][tid];
        __syncthreads();
        u.r.red[tid] = a;
    }
    __syncthreads();

    // ---- f2out matvec1: v = ssp(agg @ fw1 + fb1) ----
    {
        float p[4] = {0.f, 0.f, 0.f, 0.f};
        #pragma unroll 1
        for (int hh = 0; hh < 64; hh += 8) {
            const int h0 = ty * 64 + hh;
            float4 fq[8];
            #pragma unroll
            for (int j = 0; j < 8; ++j)
                fq[j] = *reinterpret_cast<const float4*>(&fw1[(h0 + j) * Ff + f4]);
            const float4 a0 = *reinterpret_cast<const float4*>(&u.r.red[h0]);
            const float4 a1 = *reinterpret_cast<const float4*>(&u.r.red[h0 + 4]);
            FMA4(p, a0.x, fq[0]); FMA4(p, a0.y, fq[1]);
            FMA4(p, a0.z, fq[2]); FMA4(p, a0.w, fq[3]);
            FMA4(p, a1.x, fq[4]); FMA4(p, a1.y, fq[5]);
            FMA4(p, a1.z, fq[6]); FMA4(p, a1.w, fq[7]);
        }
        *reinterpret_cast<float4*>(&u.r.p4[ty][f4]) = make_float4(p[0], p[1], p[2], p[3]);
    }
    __syncthreads();
    {
        const float uv = u.r.p4[0][tid] + u.r.p4[1][tid] + u.r.p4[2][tid]
                       + u.r.p4[3][tid] + fb1[tid];
        const float sval = ssp_f(uv);
        __syncthreads();
        u.r.red[tid] = sval;
    }
    __syncthreads();

    // ---- f2out matvec2 + residual ----
    {
        float p[4] = {0.f, 0.f, 0.f, 0.f};
        #pragma unroll 1
        for (int hh = 0; hh < 64; hh += 8) {
            const int h0 = ty * 64 + hh;
            float4 fq[8];
            #pragma unroll
            for (int j = 0; j < 8; ++j)
                fq[j] = *reinterpret_cast<const float4*>(&fw2[(h0 + j) * Ff + f4]);
            const float4 a0 = *reinterpret_cast<const float4*>(&u.r.red[h0]);
            const float4 a1 = *reinterpret_cast<const float4*>(&u.r.red[h0 + 4]);
            FMA4(p, a0.x, fq[0]); FMA4(p, a0.y, fq[1]);
            FMA4(p, a0.z, fq[2]); FMA4(p, a0.w, fq[3]);
            FMA4(p, a1.x, fq[4]); FMA4(p, a1.y, fq[5]);
            FMA4(p, a1.z, fq[6]); FMA4(p, a1.w, fq[7]);
        }
        *reinterpret_cast<float4*>(&u.r.p4[ty][f4]) = make_float4(p[0], p[1], p[2], p[3]);
    }
    __syncthreads();
    {
        const float o = u.r.p4[0][tid] + u.r.p4[1][tid] + u.r.p4[2][tid]
                      + u.r.p4[3][tid] + fb2[tid];
        x[bn * Ff + tid] += o;
    }
}

// ---------------------------------------------------------------------------
// k_head: disp/frac/rep, predictor MLP, masked mean, new_cell, new_pos
// ---------------------------------------------------------------------------
__global__ __launch_bounds__(128) void k_head(
    const float* __restrict__ x, const float* __restrict__ pos,
    const float* __restrict__ cell, const float* __restrict__ amask,
    const float* __restrict__ fdw, const float* __restrict__ fdb,
    const float* __restrict__ pw1, const float* __restrict__ pb1,
    const float* __restrict__ pw2, const float* __restrict__ pb2,
    float* __restrict__ out_pos, float* __restrict__ out_cell)
{
    const int b = blockIdx.x;
    const int n = threadIdx.x;

    __shared__ float sinv[9];
    __shared__ float scell[9];
    __shared__ float snc[9];
    __shared__ float sred[Nn][10];

    if (n == 0) {
        float c[9];
        #pragma unroll
        for (int i = 0; i < 9; ++i) { c[i] = cell[b * 9 + i]; scell[i] = c[i]; }
        float det = c[0] * (c[4] * c[8] - c[5] * c[7])
                  - c[1] * (c[3] * c[8] - c[5] * c[6])
                  + c[2] * (c[3] * c[7] - c[4] * c[6]);
        float id = 1.0f / det;
        sinv[0] = (c[4] * c[8] - c[5] * c[7]) * id;
        sinv[1] = (c[2] * c[7] - c[1] * c[8]) * id;
        sinv[2] = (c[1] * c[5] - c[2] * c[4]) * id;
        sinv[3] = (c[5] * c[6] - c[3] * c[8]) * id;
        sinv[4] = (c[0] * c[8] - c[2] * c[6]) * id;
        sinv[5] = (c[2] * c[3] - c[0] * c[5]) * id;
        sinv[6] = (c[3] * c[7] - c[4] * c[6]) * id;
        sinv[7] = (c[1] * c[6] - c[0] * c[7]) * id;
        sinv[8] = (c[0] * c[4] - c[1] * c[3]) * id;
    }
    __syncthreads();

    float xv0 = 0.f, xv1 = 0.f, xv2 = 0.f;
    const int row = (b * Nn + n) * Ff;
    for (int ff = 0; ff < Ff; ++ff) {
        float xr = x[row + ff];
        xv0 = fmaf(xr, fdw[ff * 3 + 0], xv0);
        xv1 = fmaf(xr, fdw[ff * 3 + 1], xv1);
        xv2 = fmaf(xr, fdw[ff * 3 + 2], xv2);
    }
    float fr[3];
    float dsp[3] = {xv0, xv1, xv2};
    const float p0 = pos[(b * Nn + n) * 3 + 0];
    const float p1 = pos[(b * Nn + n) * 3 + 1];
    const float p2 = pos[(b * Nn + n) * 3 + 2];
    #pragma unroll
    for (int j = 0; j < 3; ++j) {
        float z = 10.0f * (dsp[j] + fdb[j]);
        float s = 1.0f / (1.0f + expf(-z));
        float fx = p0 * sinv[0 * 3 + j] + p1 * sinv[1 * 3 + j] + p2 * sinv[2 * 3 + j] + s;
        fr[j] = fx - floorf(fx);
    }

    float rep[3];
    #pragma unroll
    for (int j = 0; j < 3; ++j)
        rep[j] = fr[0] * scell[0 * 3 + j] + fr[1] * scell[1 * 3 + j] + fr[2] * scell[2 * 3 + j];

    float a6[6];
    #pragma unroll
    for (int i = 0; i < 6; ++i) {
        float uv = rep[0] * pw1[0 * 6 + i] + rep[1] * pw1[1 * 6 + i]
                 + rep[2] * pw1[2 * 6 + i] + pb1[i];
        a6[i] = ssp_f(uv);
    }
    float h9[9];
    #pragma unroll
    for (int o = 0; o < 9; ++o) {
        float uv = pb2[o];
        #pragma unroll
        for (int i = 0; i < 6; ++i) uv = fmaf(a6[i], pw2[i * 9 + o], uv);
        h9[o] = uv;
    }

    const float m = amask[b * Nn + n];
    #pragma unroll
    for (int o = 0; o < 9; ++o) sred[n][o] = h9[o] * m;
    sred[n][9] = m;
    __syncthreads();

    for (int s = 64; s >= 1; s >>= 1) {
        if (n < s) {
            #pragma unroll
            for (int o = 0; o < 10; ++o) sred[n][o] += sred[n + s][o];
        }
        __syncthreads();
    }

    if (n < 9) {
        float na = sred[0][9];
        float yo = sred[0][n] / na;
        float scale = 3.0f * powf(na, 1.0f / 3.0f);
        int r = n / 3, c = n - r * 3;
        float v = scale * (((r == c) ? 1.0f : 0.0f) + yo);
        snc[n] = v;
        out_cell[b * 9 + n] = v;
    }
    __syncthreads();

    #pragma unroll
    for (int j = 0; j < 3; ++j) {
        float v = fr[0] * snc[0 * 3 + j] + fr[1] * snc[1 * 3 + j] + fr[2] * snc[2 * 3 + j];
        out_pos[(b * Nn + n) * 3 + j] = v;
    }
}

// ---------------------------------------------------------------------------
extern "C" void kernel_launch(void* const* d_in, const int* in_sizes, int n_in,
                              void* d_out, int out_size, void* d_ws, size_t ws_size,
                              hipStream_t stream)
{
    const float* positions     = (const float*)d_in[0];
    const float* cell          = (const float*)d_in[1];
    const int*   atomic_nums   = (const int*)  d_in[2];
    const int*   neighbors     = (const int*)  d_in[3];
    const float* neighbor_mask = (const float*)d_in[4];
    const float* atom_mask     = (const float*)d_in[5];
    const float* embedding     = (const float*)d_in[6];
    const float* filt_w1       = (const float*)d_in[7];
    const float* filt_b1       = (const float*)d_in[8];
    const float* filt_w2       = (const float*)d_in[9];
    const float* filt_b2       = (const float*)d_in[10];
    const float* in2f_w        = (const float*)d_in[11];
    const float* f2out_w1      = (const float*)d_in[12];
    const float* f2out_b1      = (const float*)d_in[13];
    const float* f2out_w2      = (const float*)d_in[14];
    const float* f2out_b2      = (const float*)d_in[15];
    const float* fd_w          = (const float*)d_in[16];
    const float* fd_b          = (const float*)d_in[17];
    const float* pred_w1       = (const float*)d_in[18];
    const float* pred_b1       = (const float*)d_in[19];
    const float* pred_w2       = (const float*)d_in[20];
    const float* pred_b2       = (const float*)d_in[21];

    float* ws   = (float*)d_ws;
    float* x    = ws;
    float* y    = x + Bb * Nn * Ff;
    float* fexp = y + Bb * Nn * Ff;
    float* fcut = fexp + Bb * Nn * Kk * Gg;

    float* out_pos  = (float*)d_out;
    float* out_cell = out_pos + Bb * Nn * 3;

    const int BN = Bb * Nn;

    k_setup<<<BN, 256, 0, stream>>>(positions, atomic_nums, neighbors,
                                    neighbor_mask, embedding, x, fexp, fcut);

    for (int t = 0; t < Tt; ++t) {
        k_y<<<BN, 256, 0, stream>>>(x, in2f_w + (size_t)t * Ff * Ff, y);
        k_agg<<<BN, 256, 0, stream>>>(fexp, fcut, neighbors, y,
                                      filt_w1 + (size_t)t * Gg * Ff,
                                      filt_b1 + (size_t)t * Ff,
                                      filt_w2 + (size_t)t * Ff * Ff,
                                      filt_b2 + (size_t)t * Ff,
                                      f2out_w1 + (size_t)t * Ff * Ff,
                                      f2out_b1 + (size_t)t * Ff,
                                      f2out_w2 + (size_t)t * Ff * Ff,
                                      f2out_b2 + (size_t)t * Ff,
                                      x);
    }

    k_head<<<Bb, 128, 0, stream>>>(x, positions, cell, atom_mask,
                                   fd_w, fd_b, pred_w1, pred_b1, pred_w2, pred_b2,
                                   out_pos, out_cell);
}